// Round 6
// baseline (172.706 us; speedup 1.0000x reference)
//
#include <hip/hip_runtime.h>

#define NJ 128   // images
#define NI 128   // captions
#define NR 36    // regions
#define NW 32    // words
#define ND 1024  // feature dim

#define LAM_SM 9.0f
#define LAM_LSE 6.0f
#define MARGIN 0.2f
#define EPSF 1e-8f

typedef __attribute__((ext_vector_type(8))) short s16x8;
typedef __attribute__((ext_vector_type(4))) float f32x4;

#define IM_ROWS (NJ * NR)          // 4608
#define S_ROWS  (NI * NW)          // 4096
#define IM_ELEMS (IM_ROWS * ND)
#define S_ELEMS  (S_ROWS * ND)
#define GSW_ELEMS (NJ * 48 * 64)   // bf16, swizzled, zero-padded

// pair3 LDS map (dynamic, 139264 B):
//   buf0 [0,69632): A 288x128B [0,36864) + B 256x128B [36864,69632)
//   buf1 [69632,139264): same
//   epilogue overlay: Gd 8x6144 [0,49152) | E 16 slots x 4096 [49152,114688)
//                     | NB f32 [8 caps][288] [114688,123904)
#define BUFSZ 69632
#define E_OFF 49152
#define NB_OFF 114688
#define SMEM_TOTAL 139264

__device__ __forceinline__ float dot4(float4 a, float4 b) {
    return a.x * b.x + a.y * b.y + a.z * b.z + a.w * b.w;
}
__device__ __forceinline__ unsigned short f2bf(float x) {
    unsigned u = __float_as_uint(x);
    return (unsigned short)((u + 0x7FFFu + ((u >> 16) & 1u)) >> 16);
}
__device__ __forceinline__ unsigned pack2bf(float x, float y) {
    return (unsigned)f2bf(x) | ((unsigned)f2bf(y) << 16);
}
__device__ __forceinline__ float bf2f(unsigned v) {
    return __uint_as_float((v & 0xffffu) << 16);
}
__device__ __forceinline__ void gload16(const void* g, void* l) {
    __builtin_amdgcn_global_load_lds((const __attribute__((address_space(1))) unsigned int*)g,
                                     (__attribute__((address_space(3))) unsigned int*)l, 16, 0, 0);
}

// ---- f32 -> bf16 convert + per-64-window chunk XOR swizzle (key = global row & 7) ----
__global__ __launch_bounds__(256) void cvtswz_kernel(const float* __restrict__ src,
                                                     unsigned short* __restrict__ dst) {
    int idx = blockIdx.x * 256 + threadIdx.x;
    int row = idx >> 7, cw = idx & 127;
    int wd = cw >> 3, p = cw & 7;
    int sk = wd * 64 + ((p ^ (row & 7)) * 8);
    const float* sp = src + (size_t)row * 1024 + sk;
    float4 v0 = *(const float4*)sp;
    float4 v1 = *(const float4*)(sp + 4);
    ushort4 o0, o1;
    o0.x = f2bf(v0.x); o0.y = f2bf(v0.y); o0.z = f2bf(v0.z); o0.w = f2bf(v0.w);
    o1.x = f2bf(v1.x); o1.y = f2bf(v1.y); o1.z = f2bf(v1.z); o1.w = f2bf(v1.w);
    ((ushort4*)dst)[idx * 2] = o0;
    ((ushort4*)dst)[idx * 2 + 1] = o1;
}

// ---- word norms w1[i][w] = ||s[i,w,:]|| (f32 exact) ----
__global__ __launch_bounds__(256) void wnorm_kernel(const float* __restrict__ s,
                                                    float* __restrict__ w1) {
    const int i = blockIdx.x;
    const int tid = threadIdx.x;
    const int w = tid >> 3;
    const int part = tid & 7;
    const float* sw = s + ((size_t)i * NW + w) * ND;
    float acc = 0.f;
    for (int k = 0; k < 32; ++k) {
        int c = (part + k * 8) * 4;
        float4 v = *(const float4*)(sw + c);
        acc += v.x * v.x + v.y * v.y + v.z * v.z + v.w * v.w;
    }
    acc += __shfl_xor(acc, 1);
    acc += __shfl_xor(acc, 2);
    acc += __shfl_xor(acc, 4);
    if (part == 0) w1[i * NW + w] = sqrtf(acc);
}

// ---- Gram via MFMA: Gsw[j] = bf16 swizzled 48x64 (rows/cols >=36 zero) ----
__global__ __launch_bounds__(64) void gram_mfma_kernel(const unsigned short* __restrict__ imsw,
                                                       unsigned short* __restrict__ Gsw) {
    const int j = blockIdx.x;
    const int l = threadIdx.x;
    const int grp = l >> 4, lw = l & 15;
    __shared__ __align__(16) char sm[6144 + 48 * 52 * 4];
    float* Gtmp = (float*)(sm + 6144);
    {
        int idx = l;
        for (int t = 0; t < 2; ++t, idx += 64) {
            if (idx < 96) {
                int row = 36 + (idx >> 3), p = idx & 7;
                *(int4*)(sm + row * 128 + p * 16) = make_int4(0, 0, 0, 0);
            }
        }
    }
    const int keyadj = (j & 1) * 4;
    const char* src = (const char*)imsw + ((size_t)j * 36 + (l >> 3)) * 2048 + (l & 7) * 16;
    f32x4 acc[3][3];
#pragma unroll
    for (int m = 0; m < 3; ++m)
#pragma unroll
        for (int n = 0; n < 3; ++n) acc[m][n] = (f32x4){0.f, 0.f, 0.f, 0.f};

    for (int k0b = 0; k0b < 2048; k0b += 128) {
        asm volatile("s_waitcnt vmcnt(0) lgkmcnt(0)" ::: "memory");
        __syncthreads();
#pragma unroll
        for (int t = 0; t < 5; ++t) {
            if (t < 4 || l < 32) gload16(src + t * 8 * 2048 + k0b, sm + t * 1024);
        }
        asm volatile("s_waitcnt vmcnt(0)" ::: "memory");
        __syncthreads();
#pragma unroll
        for (int ks = 0; ks < 2; ++ks) {
            int swz = (((ks * 4 + grp) ^ ((lw + keyadj) & 7)) << 4);
            s16x8 fr[3];
#pragma unroll
            for (int m = 0; m < 3; ++m)
                fr[m] = *(const s16x8*)(sm + m * 2048 + lw * 128 + swz);
#pragma unroll
            for (int m = 0; m < 3; ++m)
#pragma unroll
                for (int n = 0; n < 3; ++n)
                    acc[m][n] = __builtin_amdgcn_mfma_f32_16x16x32_bf16(fr[m], fr[n], acc[m][n], 0, 0, 0);
        }
    }
#pragma unroll
    for (int m = 0; m < 3; ++m)
#pragma unroll
        for (int n = 0; n < 3; ++n)
#pragma unroll
            for (int reg = 0; reg < 4; ++reg)
                Gtmp[(m * 16 + grp * 4 + reg) * 52 + n * 16 + lw] = acc[m][n][reg];
    asm volatile("s_waitcnt lgkmcnt(0)" ::: "memory");
    __syncthreads();
    for (int t = 0; t < 6; ++t) {
        int idx = l + 64 * t;
        int row = idx >> 3, p = idx & 7;
        int k0 = (p ^ (row & 7)) * 8;
        ushort4 o0, o1;
        float v[8];
#pragma unroll
        for (int e = 0; e < 8; ++e) {
            int k = k0 + e;
            v[e] = (k < 48) ? Gtmp[row * 52 + k] : 0.f;
        }
        o0.x = f2bf(v[0]); o0.y = f2bf(v[1]); o0.z = f2bf(v[2]); o0.w = f2bf(v[3]);
        o1.x = f2bf(v[4]); o1.y = f2bf(v[5]); o1.z = f2bf(v[6]); o1.w = f2bf(v[7]);
        ushort4* dp = (ushort4*)((char*)Gsw + (size_t)j * 6144 + row * 128 + p * 16);
        dp[0] = o0; dp[1] = o1;
    }
}

// ---- main pair kernel: block = 8 images x 8 captions, 8 waves (2M x 4N) ----
// amdgpu_waves_per_eu(2,2): dynamic LDS blinds the backend's occupancy model —
// it otherwise pins 4 waves/EU -> 128 VGPRs -> spills the 144-VGPR accumulator
// (R3-R5: 107MB scratch WRITE_SIZE). LDS (136KB) caps at 1 block/CU = 2 waves/EU
// anyway, so force the 256-VGPR budget.
__global__ __attribute__((amdgpu_flat_work_group_size(512, 512)))
__attribute__((amdgpu_waves_per_eu(2, 2)))
void pair3_kernel(const unsigned short* __restrict__ imsw,
                  const unsigned short* __restrict__ ssw,
                  const unsigned short* __restrict__ Gswp,
                  const float* __restrict__ w1g,
                  float* __restrict__ scores) {
    extern __shared__ char smem[];
    const int ig = blockIdx.x;   // caption octet
    const int jg = blockIdx.y;   // image octet
    const int tid = threadIdx.x;
    const int l = tid & 63, wv = tid >> 6;
    const int grp = l >> 4, lw = l & 15;
    const int wm = wv >> 2, wn = wv & 3;

    const char* aSrc = (const char*)imsw + ((size_t)(jg * 288) + (l >> 3)) * 2048 + (l & 7) * 16;
    const char* bSrc = (const char*)ssw + ((size_t)(ig * 256) + (l >> 3)) * 2048 + (l & 7) * 16;

    f32x4 acc[9][4];
#pragma unroll
    for (int m = 0; m < 9; ++m)
#pragma unroll
        for (int n = 0; n < 4; ++n) acc[m][n] = (f32x4){0.f, 0.f, 0.f, 0.f};

    auto stage = [&](int bb, int k0b) {
        char* ab = smem + bb;
#pragma unroll
        for (int t = 0; t < 5; ++t) {
            int ii = wv + 8 * t;
            if (ii < 36) gload16(aSrc + (size_t)ii * 16384 + k0b, ab + ii * 1024);
        }
        char* bbp = smem + bb + 36864;
#pragma unroll
        for (int t = 0; t < 4; ++t) {
            int ii = wv + 8 * t;
            gload16(bSrc + (size_t)ii * 16384 + k0b, bbp + ii * 1024);
        }
    };
    auto compute = [&](int bb) {
        const char* A = smem + bb;
        const char* B = smem + bb + 36864;
#pragma unroll
        for (int ks = 0; ks < 2; ++ks) {
            const int swz = (((ks * 4 + grp) ^ (lw & 7)) << 4);
            s16x8 af[9], bf[4];
#pragma unroll
            for (int m = 0; m < 9; ++m)
                af[m] = *(const s16x8*)(A + (wm * 144 + m * 16 + lw) * 128 + swz);
#pragma unroll
            for (int n = 0; n < 4; ++n)
                bf[n] = *(const s16x8*)(B + (wn * 64 + n * 16 + lw) * 128 + swz);
#pragma unroll
            for (int m = 0; m < 9; ++m)
#pragma unroll
                for (int n = 0; n < 4; ++n)
                    acc[m][n] = __builtin_amdgcn_mfma_f32_16x16x32_bf16(af[m], bf[n], acc[m][n], 0, 0, 0);
        }
    };

    stage(0, 0);
    asm volatile("s_waitcnt vmcnt(0)" ::: "memory");
    __syncthreads();
    for (int t = 0; t < 16; ++t) {
        if (t < 15) {
            stage(((t + 1) & 1) * BUFSZ, (t + 1) * 128);
        } else {
            // prefetch Gram tiles for the 8 images into dead buf0
            const char* gB = (const char*)Gswp + (size_t)jg * 49152 + l * 16;
#pragma unroll
            for (int u = 0; u < 6; ++u) {
                int ii = wv + 8 * u;
                gload16(gB + (size_t)ii * 1024, smem + ii * 1024);
            }
        }
        compute((t & 1) * BUFSZ);
        asm volatile("s_waitcnt vmcnt(0)" ::: "memory");
        __syncthreads();
    }

    // ================= barrier-free per-wave epilogue =================
    // wave (wm,wn): rows wm*144..+144 (images wm*4..+4), caps wn*2, wn*2+1
    char* myE[2];
    myE[0] = smem + E_OFF + (wm * 8 + wn * 2) * 4096;
    myE[1] = myE[0] + 4096;
    float* NB = (float*)(smem + NB_OFF);

    // zero E pads (regions 36..63) for my 2 slots
#pragma unroll
    for (int c = 0; c < 2; ++c) {
        char* Eb = myE[c];
#pragma unroll
        for (int u = 0; u < 7; ++u) {
            int e = l + u * 64;               // 448 = 32w * 14 pairs
            int w = e / 14, pr = e - w * 14 + 18;
            *(unsigned*)(Eb + w * 128 + (((pr >> 2) ^ (w & 7)) << 4) + (pr & 3) * 4) = 0u;
        }
    }

    // P1: inverse region norms (leaky, over 32 words) -> NB[cap][288]
#pragma unroll
    for (int m = 0; m < 9; ++m)
#pragma unroll
        for (int reg = 0; reg < 4; ++reg) {
            int rowL = m * 16 + grp * 4 + reg;
#pragma unroll
            for (int c = 0; c < 2; ++c) {
                float a0 = acc[m][2 * c][reg], a1 = acc[m][2 * c + 1][reg];
                float l0 = a0 > 0.f ? a0 : 0.1f * a0;
                float l1 = a1 > 0.f ? a1 : 0.1f * a1;
                float ss = l0 * l0 + l1 * l1;
                ss += __shfl_xor(ss, 1); ss += __shfl_xor(ss, 2);
                ss += __shfl_xor(ss, 4); ss += __shfl_xor(ss, 8);
                if (lw == 0)
                    NB[(wn * 2 + c) * 288 + wm * 144 + rowL] = 1.f / (sqrtf(ss) + EPSF);
            }
        }

    // P2: per-local-image per-word max logit
    float mx[4][4];
#pragma unroll
    for (int a = 0; a < 4; ++a)
#pragma unroll
        for (int b = 0; b < 4; ++b) mx[a][b] = -1e30f;
#pragma unroll
    for (int m = 0; m < 9; ++m) {
        int rbase = m * 16 + grp * 4;
        int img = (rbase * 1821) >> 16;      // rbase / 36
#pragma unroll
        for (int c = 0; c < 2; ++c) {
            float4 iv = *(const float4*)&NB[(wn * 2 + c) * 288 + wm * 144 + rbase];
            float ivr[4] = {iv.x, iv.y, iv.z, iv.w};
#pragma unroll
            for (int nn = 0; nn < 2; ++nn) {
                int n = c * 2 + nn;
                float t4 = -1e30f;
#pragma unroll
                for (int reg = 0; reg < 4; ++reg) {
                    float a = acc[m][n][reg];
                    float lk = a > 0.f ? a : 0.1f * a;
                    t4 = fmaxf(t4, LAM_SM * lk * ivr[reg]);
                }
#pragma unroll
                for (int mm = 0; mm < 4; ++mm)
                    mx[mm][n] = (img == mm) ? fmaxf(mx[mm][n], t4) : mx[mm][n];
            }
        }
    }
#pragma unroll
    for (int a = 0; a < 4; ++a)
#pragma unroll
        for (int b = 0; b < 4; ++b) {
            mx[a][b] = fmaxf(mx[a][b], __shfl_xor(mx[a][b], 16));
            mx[a][b] = fmaxf(mx[a][b], __shfl_xor(mx[a][b], 32));
        }

    float w1v[4];
#pragma unroll
    for (int n = 0; n < 4; ++n)
        w1v[n] = w1g[(ig * 8 + wn * 2 + (n >> 1)) * 32 + (n & 1) * 16 + lw];

#pragma unroll
    for (int L = 0; L < 4; ++L) {
        const int mlo = (L * 36) >> 4, mhi = (L * 36 + 35) >> 4;
        float dn[4] = {0.f, 0.f, 0.f, 0.f}, nm[4] = {0.f, 0.f, 0.f, 0.f};
        // P3: e = exp(t - mx), accumulate den/num, write E (bf16)
#pragma unroll
        for (int m = mlo; m <= mhi; ++m) {
            int rbase = m * 16 + grp * 4;
            int img = (rbase * 1821) >> 16;
            bool pred = (img == L);
            int rp0 = rbase - L * 36;
#pragma unroll
            for (int c = 0; c < 2; ++c) {
                float4 iv = *(const float4*)&NB[(wn * 2 + c) * 288 + wm * 144 + rbase];
                float ivr[4] = {iv.x, iv.y, iv.z, iv.w};
#pragma unroll
                for (int nn = 0; nn < 2; ++nn) {
                    int n = c * 2 + nn;
                    int w = nn * 16 + lw;
                    float e[4];
#pragma unroll
                    for (int reg = 0; reg < 4; ++reg) {
                        float a = acc[m][n][reg];
                        float lk = a > 0.f ? a : 0.1f * a;
                        float tl = LAM_SM * lk * ivr[reg];
                        e[reg] = pred ? __expf(tl - mx[L][n]) : 0.f;
                        dn[n] += e[reg];
                        nm[n] += e[reg] * a;
                    }
                    if (pred) {
                        char* base = myE[c] + w * 128 + (((rp0 >> 3) ^ (w & 7)) << 4) + (rp0 & 7) * 2;
                        *(unsigned*)(base) = pack2bf(e[0], e[1]);
                        *(unsigned*)(base + 4) = pack2bf(e[2], e[3]);
                    }
                }
            }
        }
#pragma unroll
        for (int n = 0; n < 4; ++n) {
            dn[n] += __shfl_xor(dn[n], 16); dn[n] += __shfl_xor(dn[n], 32);
            nm[n] += __shfl_xor(nm[n], 16); nm[n] += __shfl_xor(nm[n], 32);
        }
        // P4: U = Gd[img] x E ; q = sum E .* U
        const char* Gd = smem + (wm * 4 + L) * 6144;
        f32x4 u[3][4];
#pragma unroll
        for (int m = 0; m < 3; ++m)
#pragma unroll
            for (int n = 0; n < 4; ++n) u[m][n] = (f32x4){0.f, 0.f, 0.f, 0.f};
#pragma unroll
        for (int ks = 0; ks < 2; ++ks) {
            int swz = (((ks * 4 + grp) ^ (lw & 7)) << 4);
            s16x8 ga[3], eb[4];
#pragma unroll
            for (int m = 0; m < 3; ++m)
                ga[m] = *(const s16x8*)(Gd + (m * 16 + lw) * 128 + swz);
#pragma unroll
            for (int n = 0; n < 4; ++n) {
                int w = (n & 1) * 16 + lw;
                eb[n] = *(const s16x8*)(myE[n >> 1] + w * 128 + (((ks * 4 + grp) ^ (w & 7)) << 4));
            }
#pragma unroll
            for (int m = 0; m < 3; ++m)
#pragma unroll
                for (int n = 0; n < 4; ++n)
                    u[m][n] = __builtin_amdgcn_mfma_f32_16x16x32_bf16(ga[m], eb[n], u[m][n], 0, 0, 0);
        }
        float qq[4] = {0.f, 0.f, 0.f, 0.f};
#pragma unroll
        for (int m = 0; m < 3; ++m)
#pragma unroll
            for (int n = 0; n < 4; ++n) {
                int w = (n & 1) * 16 + lw;
                const char* base = myE[n >> 1] + w * 128;
#pragma unroll
                for (int rg = 0; rg < 4; rg += 2) {
                    int rp = m * 16 + grp * 4 + rg;
                    unsigned pv = *(const unsigned*)(base + (((rp >> 3) ^ (w & 7)) << 4) + (rp & 7) * 2);
                    qq[n] += u[m][n][rg] * bf2f(pv) + u[m][n][rg + 1] * bf2f(pv >> 16);
                }
            }
#pragma unroll
        for (int n = 0; n < 4; ++n) {
            qq[n] += __shfl_xor(qq[n], 16); qq[n] += __shfl_xor(qq[n], 32);
        }
        // P5: cosine sim + LSE over 32 words -> score
        float sim[4];
#pragma unroll
        for (int n = 0; n < 4; ++n)
            sim[n] = nm[n] / fmaxf(w1v[n] * sqrtf(fmaxf(qq[n], 0.f)), EPSF * dn[n]);
#pragma unroll
        for (int c2 = 0; c2 < 2; ++c2) {
            float s0 = sim[c2 * 2], s1 = sim[c2 * 2 + 1];
            float m2 = fmaxf(s0, s1);
            m2 = fmaxf(m2, __shfl_xor(m2, 1)); m2 = fmaxf(m2, __shfl_xor(m2, 2));
            m2 = fmaxf(m2, __shfl_xor(m2, 4)); m2 = fmaxf(m2, __shfl_xor(m2, 8));
            float ssum = __expf(LAM_LSE * (s0 - m2)) + __expf(LAM_LSE * (s1 - m2));
            ssum += __shfl_xor(ssum, 1); ssum += __shfl_xor(ssum, 2);
            ssum += __shfl_xor(ssum, 4); ssum += __shfl_xor(ssum, 8);
            if (l == 0)
                scores[(size_t)(jg * 8 + wm * 4 + L) * NI + ig * 8 + wn * 2 + c2] =
                    m2 + logf(ssum) / LAM_LSE;
        }
    }
}

// ---- final hinge loss over the 128x128 score matrix ----
__global__ __launch_bounds__(256) void loss_kernel(const float* __restrict__ scores,
                                                   float* __restrict__ out) {
    __shared__ float diag[NJ];
    __shared__ float part[256];
    const int tid = threadIdx.x;
    if (tid < NJ) diag[tid] = scores[tid * NI + tid];
    __syncthreads();
    float m = 0.f;
    if (tid < 128) {
        const int a = tid;
        const float da = diag[a];
        for (int b = 0; b < NI; ++b) {
            if (b == a) continue;
            float c = MARGIN + scores[a * NI + b] - da;
            m = fmaxf(m, c);
        }
    } else {
        const int b = tid - 128;
        const float db = diag[b];
        for (int a = 0; a < NJ; ++a) {
            if (a == b) continue;
            float c = MARGIN + scores[a * NI + b] - db;
            m = fmaxf(m, c);
        }
    }
    part[tid] = m;
    __syncthreads();
    for (int st = 128; st > 0; st >>= 1) {
        if (tid < st) part[tid] += part[tid + st];
        __syncthreads();
    }
    if (tid == 0) out[0] = part[0];
}

extern "C" void kernel_launch(void* const* d_in, const int* in_sizes, int n_in,
                              void* d_out, int out_size, void* d_ws, size_t ws_size,
                              hipStream_t stream) {
    const float* im = (const float*)d_in[0];
    const float* s = (const float*)d_in[1];

    unsigned short* imsw = (unsigned short*)d_ws;
    unsigned short* ssw = imsw + IM_ELEMS;
    unsigned short* Gswp = ssw + S_ELEMS;
    float* w1 = (float*)(Gswp + GSW_ELEMS);
    float* scores = w1 + S_ROWS;

    hipFuncSetAttribute((const void*)pair3_kernel,
                        hipFuncAttributeMaxDynamicSharedMemorySize, SMEM_TOTAL);

    cvtswz_kernel<<<dim3(IM_ROWS * 128 / 256), dim3(256), 0, stream>>>(im, imsw);
    cvtswz_kernel<<<dim3(S_ROWS * 128 / 256), dim3(256), 0, stream>>>(s, ssw);
    wnorm_kernel<<<dim3(NI), dim3(256), 0, stream>>>(s, w1);
    gram_mfma_kernel<<<dim3(NJ), dim3(64), 0, stream>>>(imsw, Gswp);
    pair3_kernel<<<dim3(NI / 8, NJ / 8), dim3(512), SMEM_TOTAL, stream>>>(imsw, ssw, Gswp, w1, scores);
    loss_kernel<<<dim3(1), dim3(256), 0, stream>>>(scores, (float*)d_out);
}

// Round 7
// 172.679 us; speedup vs baseline: 1.0002x; 1.0002x over previous
//
#include <hip/hip_runtime.h>

#define NJ 128   // images
#define NI 128   // captions
#define NR 36    // regions
#define NW 32    // words
#define ND 1024  // feature dim

#define LAM_SM 9.0f
#define LAM_LSE 6.0f
#define MARGIN 0.2f
#define EPSF 1e-8f

typedef __attribute__((ext_vector_type(8))) short s16x8;
typedef __attribute__((ext_vector_type(4))) float f32x4;

#define IM_ROWS (NJ * NR)          // 4608
#define S_ROWS  (NI * NW)          // 4096
#define IM_ELEMS (IM_ROWS * ND)
#define S_ELEMS  (S_ROWS * ND)
#define GSW_ELEMS (NJ * 48 * 64)   // bf16, swizzled, zero-padded

// pair3 LDS map (dynamic, 139264 B):
//   buf0 [0,69632): A 288x128B [0,36864) + B 256x128B [36864,69632)
//   buf1 [69632,139264): same
//   epilogue overlay: Gd 8x6144 [0,49152) | E 16 slots x 4096 [49152,114688)
//                     | NB f32 [8 caps][288] [114688,123904)
#define BUFSZ 69632
#define E_OFF 49152
#define NB_OFF 114688
#define SMEM_TOTAL 139264

__device__ __forceinline__ float dot4(float4 a, float4 b) {
    return a.x * b.x + a.y * b.y + a.z * b.z + a.w * b.w;
}
__device__ __forceinline__ unsigned short f2bf(float x) {
    unsigned u = __float_as_uint(x);
    return (unsigned short)((u + 0x7FFFu + ((u >> 16) & 1u)) >> 16);
}
__device__ __forceinline__ unsigned pack2bf(float x, float y) {
    return (unsigned)f2bf(x) | ((unsigned)f2bf(y) << 16);
}
__device__ __forceinline__ float bf2f(unsigned v) {
    return __uint_as_float((v & 0xffffu) << 16);
}
__device__ __forceinline__ void gload16(const void* g, void* l) {
    __builtin_amdgcn_global_load_lds((const __attribute__((address_space(1))) unsigned int*)g,
                                     (__attribute__((address_space(3))) unsigned int*)l, 16, 0, 0);
}

// ---- f32 -> bf16 convert + per-64-window chunk XOR swizzle (key = global row & 7) ----
__global__ __launch_bounds__(256) void cvtswz_kernel(const float* __restrict__ src,
                                                     unsigned short* __restrict__ dst) {
    int idx = blockIdx.x * 256 + threadIdx.x;
    int row = idx >> 7, cw = idx & 127;
    int wd = cw >> 3, p = cw & 7;
    int sk = wd * 64 + ((p ^ (row & 7)) * 8);
    const float* sp = src + (size_t)row * 1024 + sk;
    float4 v0 = *(const float4*)sp;
    float4 v1 = *(const float4*)(sp + 4);
    ushort4 o0, o1;
    o0.x = f2bf(v0.x); o0.y = f2bf(v0.y); o0.z = f2bf(v0.z); o0.w = f2bf(v0.w);
    o1.x = f2bf(v1.x); o1.y = f2bf(v1.y); o1.z = f2bf(v1.z); o1.w = f2bf(v1.w);
    ((ushort4*)dst)[idx * 2] = o0;
    ((ushort4*)dst)[idx * 2 + 1] = o1;
}

// ---- word norms w1[i][w] = ||s[i,w,:]|| (f32 exact) ----
__global__ __launch_bounds__(256) void wnorm_kernel(const float* __restrict__ s,
                                                    float* __restrict__ w1) {
    const int i = blockIdx.x;
    const int tid = threadIdx.x;
    const int w = tid >> 3;
    const int part = tid & 7;
    const float* sw = s + ((size_t)i * NW + w) * ND;
    float acc = 0.f;
    for (int k = 0; k < 32; ++k) {
        int c = (part + k * 8) * 4;
        float4 v = *(const float4*)(sw + c);
        acc += v.x * v.x + v.y * v.y + v.z * v.z + v.w * v.w;
    }
    acc += __shfl_xor(acc, 1);
    acc += __shfl_xor(acc, 2);
    acc += __shfl_xor(acc, 4);
    if (part == 0) w1[i * NW + w] = sqrtf(acc);
}

// ---- Gram via MFMA: Gsw[j] = bf16 swizzled 48x64 (rows/cols >=36 zero) ----
__global__ __launch_bounds__(64) void gram_mfma_kernel(const unsigned short* __restrict__ imsw,
                                                       unsigned short* __restrict__ Gsw) {
    const int j = blockIdx.x;
    const int l = threadIdx.x;
    const int grp = l >> 4, lw = l & 15;
    __shared__ __align__(16) char sm[6144 + 48 * 52 * 4];
    float* Gtmp = (float*)(sm + 6144);
    {
        int idx = l;
        for (int t = 0; t < 2; ++t, idx += 64) {
            if (idx < 96) {
                int row = 36 + (idx >> 3), p = idx & 7;
                *(int4*)(sm + row * 128 + p * 16) = make_int4(0, 0, 0, 0);
            }
        }
    }
    const int keyadj = (j & 1) * 4;
    const char* src = (const char*)imsw + ((size_t)j * 36 + (l >> 3)) * 2048 + (l & 7) * 16;
    f32x4 acc[3][3];
#pragma unroll
    for (int m = 0; m < 3; ++m)
#pragma unroll
        for (int n = 0; n < 3; ++n) acc[m][n] = (f32x4){0.f, 0.f, 0.f, 0.f};

    for (int k0b = 0; k0b < 2048; k0b += 128) {
        asm volatile("s_waitcnt vmcnt(0) lgkmcnt(0)" ::: "memory");
        __syncthreads();
#pragma unroll
        for (int t = 0; t < 5; ++t) {
            if (t < 4 || l < 32) gload16(src + t * 8 * 2048 + k0b, sm + t * 1024);
        }
        asm volatile("s_waitcnt vmcnt(0)" ::: "memory");
        __syncthreads();
#pragma unroll
        for (int ks = 0; ks < 2; ++ks) {
            int swz = (((ks * 4 + grp) ^ ((lw + keyadj) & 7)) << 4);
            s16x8 fr[3];
#pragma unroll
            for (int m = 0; m < 3; ++m)
                fr[m] = *(const s16x8*)(sm + m * 2048 + lw * 128 + swz);
#pragma unroll
            for (int m = 0; m < 3; ++m)
#pragma unroll
                for (int n = 0; n < 3; ++n)
                    acc[m][n] = __builtin_amdgcn_mfma_f32_16x16x32_bf16(fr[m], fr[n], acc[m][n], 0, 0, 0);
        }
    }
#pragma unroll
    for (int m = 0; m < 3; ++m)
#pragma unroll
        for (int n = 0; n < 3; ++n)
#pragma unroll
            for (int reg = 0; reg < 4; ++reg)
                Gtmp[(m * 16 + grp * 4 + reg) * 52 + n * 16 + lw] = acc[m][n][reg];
    asm volatile("s_waitcnt lgkmcnt(0)" ::: "memory");
    __syncthreads();
    for (int t = 0; t < 6; ++t) {
        int idx = l + 64 * t;
        int row = idx >> 3, p = idx & 7;
        int k0 = (p ^ (row & 7)) * 8;
        ushort4 o0, o1;
        float v[8];
#pragma unroll
        for (int e = 0; e < 8; ++e) {
            int k = k0 + e;
            v[e] = (k < 48) ? Gtmp[row * 52 + k] : 0.f;
        }
        o0.x = f2bf(v[0]); o0.y = f2bf(v[1]); o0.z = f2bf(v[2]); o0.w = f2bf(v[3]);
        o1.x = f2bf(v[4]); o1.y = f2bf(v[5]); o1.z = f2bf(v[6]); o1.w = f2bf(v[7]);
        ushort4* dp = (ushort4*)((char*)Gsw + (size_t)j * 6144 + row * 128 + p * 16);
        dp[0] = o0; dp[1] = o1;
    }
}

// ---- main pair kernel: block = 8 images x 8 captions, 8 waves (2M x 4N) ----
// R6 post-mortem: acc[9][4] was demoted to SCRATCH because P3's region loop
// (for m = mlo..mhi, runtime-looking bounds) runtime-indexed it (rule #20).
// That was the 104MB WRITE_SIZE. Fix: m in {2L, 2L+1, 2L+2} — fully static.
__global__ __attribute__((amdgpu_flat_work_group_size(512, 512)))
__attribute__((amdgpu_waves_per_eu(2, 2)))
void pair3_kernel(const unsigned short* __restrict__ imsw,
                  const unsigned short* __restrict__ ssw,
                  const unsigned short* __restrict__ Gswp,
                  const float* __restrict__ w1g,
                  float* __restrict__ scores) {
    extern __shared__ char smem[];
    const int ig = blockIdx.x;   // caption octet
    const int jg = blockIdx.y;   // image octet
    const int tid = threadIdx.x;
    const int l = tid & 63, wv = tid >> 6;
    const int grp = l >> 4, lw = l & 15;
    const int wm = wv >> 2, wn = wv & 3;

    const char* aSrc = (const char*)imsw + ((size_t)(jg * 288) + (l >> 3)) * 2048 + (l & 7) * 16;
    const char* bSrc = (const char*)ssw + ((size_t)(ig * 256) + (l >> 3)) * 2048 + (l & 7) * 16;

    f32x4 acc[9][4];
#pragma unroll
    for (int m = 0; m < 9; ++m)
#pragma unroll
        for (int n = 0; n < 4; ++n) acc[m][n] = (f32x4){0.f, 0.f, 0.f, 0.f};

    auto stage = [&](int bb, int k0b) {
        char* ab = smem + bb;
#pragma unroll
        for (int t = 0; t < 5; ++t) {
            int ii = wv + 8 * t;
            if (ii < 36) gload16(aSrc + (size_t)ii * 16384 + k0b, ab + ii * 1024);
        }
        char* bbp = smem + bb + 36864;
#pragma unroll
        for (int t = 0; t < 4; ++t) {
            int ii = wv + 8 * t;
            gload16(bSrc + (size_t)ii * 16384 + k0b, bbp + ii * 1024);
        }
    };
    auto compute = [&](int bb) {
        const char* A = smem + bb;
        const char* B = smem + bb + 36864;
#pragma unroll
        for (int ks = 0; ks < 2; ++ks) {
            const int swz = (((ks * 4 + grp) ^ (lw & 7)) << 4);
            s16x8 af[9], bf[4];
#pragma unroll
            for (int m = 0; m < 9; ++m)
                af[m] = *(const s16x8*)(A + (wm * 144 + m * 16 + lw) * 128 + swz);
#pragma unroll
            for (int n = 0; n < 4; ++n)
                bf[n] = *(const s16x8*)(B + (wn * 64 + n * 16 + lw) * 128 + swz);
#pragma unroll
            for (int m = 0; m < 9; ++m)
#pragma unroll
                for (int n = 0; n < 4; ++n)
                    acc[m][n] = __builtin_amdgcn_mfma_f32_16x16x32_bf16(af[m], bf[n], acc[m][n], 0, 0, 0);
        }
    };

    stage(0, 0);
    asm volatile("s_waitcnt vmcnt(0)" ::: "memory");
    __syncthreads();
    for (int t = 0; t < 16; ++t) {
        if (t < 15) {
            stage(((t + 1) & 1) * BUFSZ, (t + 1) * 128);
        } else {
            // prefetch Gram tiles for the 8 images into dead buf0
            const char* gB = (const char*)Gswp + (size_t)jg * 49152 + l * 16;
#pragma unroll
            for (int u = 0; u < 6; ++u) {
                int ii = wv + 8 * u;
                gload16(gB + (size_t)ii * 1024, smem + ii * 1024);
            }
        }
        compute((t & 1) * BUFSZ);
        asm volatile("s_waitcnt vmcnt(0)" ::: "memory");
        __syncthreads();
    }

    // ================= barrier-free per-wave epilogue =================
    // wave (wm,wn): rows wm*144..+144 (images wm*4..+4), caps wn*2, wn*2+1
    char* myE[2];
    myE[0] = smem + E_OFF + (wm * 8 + wn * 2) * 4096;
    myE[1] = myE[0] + 4096;
    float* NB = (float*)(smem + NB_OFF);

    // zero E pads (regions 36..63) for my 2 slots
#pragma unroll
    for (int c = 0; c < 2; ++c) {
        char* Eb = myE[c];
#pragma unroll
        for (int u = 0; u < 7; ++u) {
            int e = l + u * 64;               // 448 = 32w * 14 pairs
            int w = e / 14, pr = e - w * 14 + 18;
            *(unsigned*)(Eb + w * 128 + (((pr >> 2) ^ (w & 7)) << 4) + (pr & 3) * 4) = 0u;
        }
    }

    // P1: inverse region norms (leaky, over 32 words) -> NB[cap][288]
#pragma unroll
    for (int m = 0; m < 9; ++m)
#pragma unroll
        for (int reg = 0; reg < 4; ++reg) {
            int rowL = m * 16 + grp * 4 + reg;
#pragma unroll
            for (int c = 0; c < 2; ++c) {
                float a0 = acc[m][2 * c][reg], a1 = acc[m][2 * c + 1][reg];
                float l0 = a0 > 0.f ? a0 : 0.1f * a0;
                float l1 = a1 > 0.f ? a1 : 0.1f * a1;
                float ss = l0 * l0 + l1 * l1;
                ss += __shfl_xor(ss, 1); ss += __shfl_xor(ss, 2);
                ss += __shfl_xor(ss, 4); ss += __shfl_xor(ss, 8);
                if (lw == 0)
                    NB[(wn * 2 + c) * 288 + wm * 144 + rowL] = 1.f / (sqrtf(ss) + EPSF);
            }
        }

    // P2: per-local-image per-word max logit
    float mx[4][4];
#pragma unroll
    for (int a = 0; a < 4; ++a)
#pragma unroll
        for (int b = 0; b < 4; ++b) mx[a][b] = -1e30f;
#pragma unroll
    for (int m = 0; m < 9; ++m) {
        int rbase = m * 16 + grp * 4;
        int img = (rbase * 1821) >> 16;      // rbase / 36
#pragma unroll
        for (int c = 0; c < 2; ++c) {
            float4 iv = *(const float4*)&NB[(wn * 2 + c) * 288 + wm * 144 + rbase];
            float ivr[4] = {iv.x, iv.y, iv.z, iv.w};
#pragma unroll
            for (int nn = 0; nn < 2; ++nn) {
                int n = c * 2 + nn;
                float t4 = -1e30f;
#pragma unroll
                for (int reg = 0; reg < 4; ++reg) {
                    float a = acc[m][n][reg];
                    float lk = a > 0.f ? a : 0.1f * a;
                    t4 = fmaxf(t4, LAM_SM * lk * ivr[reg]);
                }
#pragma unroll
                for (int mm = 0; mm < 4; ++mm)
                    mx[mm][n] = (img == mm) ? fmaxf(mx[mm][n], t4) : mx[mm][n];
            }
        }
    }
#pragma unroll
    for (int a = 0; a < 4; ++a)
#pragma unroll
        for (int b = 0; b < 4; ++b) {
            mx[a][b] = fmaxf(mx[a][b], __shfl_xor(mx[a][b], 16));
            mx[a][b] = fmaxf(mx[a][b], __shfl_xor(mx[a][b], 32));
        }

    float w1v[4];
#pragma unroll
    for (int n = 0; n < 4; ++n)
        w1v[n] = w1g[(ig * 8 + wn * 2 + (n >> 1)) * 32 + (n & 1) * 16 + lw];

#pragma unroll
    for (int L = 0; L < 4; ++L) {
        float dn[4] = {0.f, 0.f, 0.f, 0.f}, nm[4] = {0.f, 0.f, 0.f, 0.f};
        // P3: e = exp(t - mx), accumulate den/num, write E (bf16)
        // image L's rows live in m = 2L, 2L+1, 2L+2 — STATIC indices (rule #20:
        // runtime loop bounds here demoted acc[][] to scratch in R3-R6).
#pragma unroll
        for (int mm3 = 0; mm3 < 3; ++mm3) {
            const int m = 2 * L + mm3;
            int rbase = m * 16 + grp * 4;
            int img = (rbase * 1821) >> 16;
            bool pred = (img == L);
            int rp0 = rbase - L * 36;
#pragma unroll
            for (int c = 0; c < 2; ++c) {
                float4 iv = *(const float4*)&NB[(wn * 2 + c) * 288 + wm * 144 + rbase];
                float ivr[4] = {iv.x, iv.y, iv.z, iv.w};
#pragma unroll
                for (int nn = 0; nn < 2; ++nn) {
                    int n = c * 2 + nn;
                    int w = nn * 16 + lw;
                    float e[4];
#pragma unroll
                    for (int reg = 0; reg < 4; ++reg) {
                        float a = acc[m][n][reg];
                        float lk = a > 0.f ? a : 0.1f * a;
                        float tl = LAM_SM * lk * ivr[reg];
                        e[reg] = pred ? __expf(tl - mx[L][n]) : 0.f;
                        dn[n] += e[reg];
                        nm[n] += e[reg] * a;
                    }
                    if (pred) {
                        char* base = myE[c] + w * 128 + (((rp0 >> 3) ^ (w & 7)) << 4) + (rp0 & 7) * 2;
                        *(unsigned*)(base) = pack2bf(e[0], e[1]);
                        *(unsigned*)(base + 4) = pack2bf(e[2], e[3]);
                    }
                }
            }
        }
#pragma unroll
        for (int n = 0; n < 4; ++n) {
            dn[n] += __shfl_xor(dn[n], 16); dn[n] += __shfl_xor(dn[n], 32);
            nm[n] += __shfl_xor(nm[n], 16); nm[n] += __shfl_xor(nm[n], 32);
        }
        // P4: U = Gd[img] x E ; q = sum E .* U
        const char* Gd = smem + (wm * 4 + L) * 6144;
        f32x4 u[3][4];
#pragma unroll
        for (int m = 0; m < 3; ++m)
#pragma unroll
            for (int n = 0; n < 4; ++n) u[m][n] = (f32x4){0.f, 0.f, 0.f, 0.f};
#pragma unroll
        for (int ks = 0; ks < 2; ++ks) {
            int swz = (((ks * 4 + grp) ^ (lw & 7)) << 4);
            s16x8 ga[3], eb[4];
#pragma unroll
            for (int m = 0; m < 3; ++m)
                ga[m] = *(const s16x8*)(Gd + (m * 16 + lw) * 128 + swz);
#pragma unroll
            for (int n = 0; n < 4; ++n) {
                int w = (n & 1) * 16 + lw;
                eb[n] = *(const s16x8*)(myE[n >> 1] + w * 128 + (((ks * 4 + grp) ^ (w & 7)) << 4));
            }
#pragma unroll
            for (int m = 0; m < 3; ++m)
#pragma unroll
                for (int n = 0; n < 4; ++n)
                    u[m][n] = __builtin_amdgcn_mfma_f32_16x16x32_bf16(ga[m], eb[n], u[m][n], 0, 0, 0);
        }
        float qq[4] = {0.f, 0.f, 0.f, 0.f};
#pragma unroll
        for (int m = 0; m < 3; ++m)
#pragma unroll
            for (int n = 0; n < 4; ++n) {
                int w = (n & 1) * 16 + lw;
                const char* base = myE[n >> 1] + w * 128;
#pragma unroll
                for (int rg = 0; rg < 4; rg += 2) {
                    int rp = m * 16 + grp * 4 + rg;
                    unsigned pv = *(const unsigned*)(base + (((rp >> 3) ^ (w & 7)) << 4) + (rp & 7) * 2);
                    qq[n] += u[m][n][rg] * bf2f(pv) + u[m][n][rg + 1] * bf2f(pv >> 16);
                }
            }
#pragma unroll
        for (int n = 0; n < 4; ++n) {
            qq[n] += __shfl_xor(qq[n], 16); qq[n] += __shfl_xor(qq[n], 32);
        }
        // P5: cosine sim + LSE over 32 words -> score
        float sim[4];
#pragma unroll
        for (int n = 0; n < 4; ++n)
            sim[n] = nm[n] / fmaxf(w1v[n] * sqrtf(fmaxf(qq[n], 0.f)), EPSF * dn[n]);
#pragma unroll
        for (int c2 = 0; c2 < 2; ++c2) {
            float s0 = sim[c2 * 2], s1 = sim[c2 * 2 + 1];
            float m2 = fmaxf(s0, s1);
            m2 = fmaxf(m2, __shfl_xor(m2, 1)); m2 = fmaxf(m2, __shfl_xor(m2, 2));
            m2 = fmaxf(m2, __shfl_xor(m2, 4)); m2 = fmaxf(m2, __shfl_xor(m2, 8));
            float ssum = __expf(LAM_LSE * (s0 - m2)) + __expf(LAM_LSE * (s1 - m2));
            ssum += __shfl_xor(ssum, 1); ssum += __shfl_xor(ssum, 2);
            ssum += __shfl_xor(ssum, 4); ssum += __shfl_xor(ssum, 8);
            if (l == 0)
                scores[(size_t)(jg * 8 + wm * 4 + L) * NI + ig * 8 + wn * 2 + c2] =
                    m2 + logf(ssum) / LAM_LSE;
        }
    }
}

// ---- final hinge loss over the 128x128 score matrix ----
__global__ __launch_bounds__(256) void loss_kernel(const float* __restrict__ scores,
                                                   float* __restrict__ out) {
    __shared__ float diag[NJ];
    __shared__ float part[256];
    const int tid = threadIdx.x;
    if (tid < NJ) diag[tid] = scores[tid * NI + tid];
    __syncthreads();
    float m = 0.f;
    if (tid < 128) {
        const int a = tid;
        const float da = diag[a];
        for (int b = 0; b < NI; ++b) {
            if (b == a) continue;
            float c = MARGIN + scores[a * NI + b] - da;
            m = fmaxf(m, c);
        }
    } else {
        const int b = tid - 128;
        const float db = diag[b];
        for (int a = 0; a < NJ; ++a) {
            if (a == b) continue;
            float c = MARGIN + scores[a * NI + b] - db;
            m = fmaxf(m, c);
        }
    }
    part[tid] = m;
    __syncthreads();
    for (int st = 128; st > 0; st >>= 1) {
        if (tid < st) part[tid] += part[tid + st];
        __syncthreads();
    }
    if (tid == 0) out[0] = part[0];
}

extern "C" void kernel_launch(void* const* d_in, const int* in_sizes, int n_in,
                              void* d_out, int out_size, void* d_ws, size_t ws_size,
                              hipStream_t stream) {
    const float* im = (const float*)d_in[0];
    const float* s = (const float*)d_in[1];

    unsigned short* imsw = (unsigned short*)d_ws;
    unsigned short* ssw = imsw + IM_ELEMS;
    unsigned short* Gswp = ssw + S_ELEMS;
    float* w1 = (float*)(Gswp + GSW_ELEMS);
    float* scores = w1 + S_ROWS;

    hipFuncSetAttribute((const void*)pair3_kernel,
                        hipFuncAttributeMaxDynamicSharedMemorySize, SMEM_TOTAL);

    cvtswz_kernel<<<dim3(IM_ROWS * 128 / 256), dim3(256), 0, stream>>>(im, imsw);
    cvtswz_kernel<<<dim3(S_ROWS * 128 / 256), dim3(256), 0, stream>>>(s, ssw);
    wnorm_kernel<<<dim3(NI), dim3(256), 0, stream>>>(s, w1);
    gram_mfma_kernel<<<dim3(NJ), dim3(64), 0, stream>>>(imsw, Gswp);
    pair3_kernel<<<dim3(NI / 8, NJ / 8), dim3(512), SMEM_TOTAL, stream>>>(imsw, ssw, Gswp, w1, scores);
    loss_kernel<<<dim3(1), dim3(256), 0, stream>>>(scores, (float*)d_out);
}

// Round 8
// 131.214 us; speedup vs baseline: 1.3162x; 1.3160x over previous
//
#include <hip/hip_runtime.h>

#define NJ 128   // images
#define NI 128   // captions
#define NR 36    // regions
#define NW 32    // words
#define ND 1024  // feature dim

#define LAM_SM 9.0f
#define LAM_LSE 6.0f
#define MARGIN 0.2f
#define EPSF 1e-8f

typedef __attribute__((ext_vector_type(8))) short s16x8;
typedef __attribute__((ext_vector_type(4))) float f32x4;

#define IM_ROWS (NJ * NR)          // 4608
#define S_ROWS  (NI * NW)          // 4096
#define IM_ELEMS (IM_ROWS * ND)
#define S_ELEMS  (S_ROWS * ND)
#define GSW_ELEMS (NJ * 48 * 64)   // bf16, swizzled, zero-padded

// pair4 LDS map (dynamic, 106496 B):
//   buf0 [0,53248): A 288x128B [0,36864) + B 128x128B [36864,53248)
//   buf1 [53248,106496): same
//   epilogue overlay: Gd 8x6144 [0,49152) | E 8 slots x 4096 [53248,86016)
//                     | NB f32 [4 caps][288] [86016,90624)
#define BUFSZ 53248
#define BOFF 36864
#define E_OFF 53248
#define NB_OFF 86016
#define SMEM_TOTAL 106496

__device__ __forceinline__ unsigned short f2bf(float x) {
    unsigned u = __float_as_uint(x);
    return (unsigned short)((u + 0x7FFFu + ((u >> 16) & 1u)) >> 16);
}
__device__ __forceinline__ unsigned pack2bf(float x, float y) {
    return (unsigned)f2bf(x) | ((unsigned)f2bf(y) << 16);
}
__device__ __forceinline__ float bf2f(unsigned v) {
    return __uint_as_float((v & 0xffffu) << 16);
}
__device__ __forceinline__ void gload16(const void* g, void* l) {
    __builtin_amdgcn_global_load_lds((const __attribute__((address_space(1))) unsigned int*)g,
                                     (__attribute__((address_space(3))) unsigned int*)l, 16, 0, 0);
}

// ---- f32 -> bf16 convert + per-64-window chunk XOR swizzle (key = global row & 7) ----
__global__ __launch_bounds__(256) void cvtswz_kernel(const float* __restrict__ src,
                                                     unsigned short* __restrict__ dst) {
    int idx = blockIdx.x * 256 + threadIdx.x;
    int row = idx >> 7, cw = idx & 127;
    int wd = cw >> 3, p = cw & 7;
    int sk = wd * 64 + ((p ^ (row & 7)) * 8);
    const float* sp = src + (size_t)row * 1024 + sk;
    float4 v0 = *(const float4*)sp;
    float4 v1 = *(const float4*)(sp + 4);
    ushort4 o0, o1;
    o0.x = f2bf(v0.x); o0.y = f2bf(v0.y); o0.z = f2bf(v0.z); o0.w = f2bf(v0.w);
    o1.x = f2bf(v1.x); o1.y = f2bf(v1.y); o1.z = f2bf(v1.z); o1.w = f2bf(v1.w);
    ((ushort4*)dst)[idx * 2] = o0;
    ((ushort4*)dst)[idx * 2 + 1] = o1;
}

// ---- word norms w1[i][w] = ||s[i,w,:]|| (f32 exact) ----
__global__ __launch_bounds__(256) void wnorm_kernel(const float* __restrict__ s,
                                                    float* __restrict__ w1) {
    const int i = blockIdx.x;
    const int tid = threadIdx.x;
    const int w = tid >> 3;
    const int part = tid & 7;
    const float* sw = s + ((size_t)i * NW + w) * ND;
    float acc = 0.f;
    for (int k = 0; k < 32; ++k) {
        int c = (part + k * 8) * 4;
        float4 v = *(const float4*)(sw + c);
        acc += v.x * v.x + v.y * v.y + v.z * v.z + v.w * v.w;
    }
    acc += __shfl_xor(acc, 1);
    acc += __shfl_xor(acc, 2);
    acc += __shfl_xor(acc, 4);
    if (part == 0) w1[i * NW + w] = sqrtf(acc);
}

// ---- Gram via MFMA: Gsw[j] = bf16 swizzled 48x64 (rows/cols >=36 zero) ----
__global__ __launch_bounds__(64) void gram_mfma_kernel(const unsigned short* __restrict__ imsw,
                                                       unsigned short* __restrict__ Gsw) {
    const int j = blockIdx.x;
    const int l = threadIdx.x;
    const int grp = l >> 4, lw = l & 15;
    __shared__ __align__(16) char sm[6144 + 48 * 52 * 4];
    float* Gtmp = (float*)(sm + 6144);
    {
        int idx = l;
        for (int t = 0; t < 2; ++t, idx += 64) {
            if (idx < 96) {
                int row = 36 + (idx >> 3), p = idx & 7;
                *(int4*)(sm + row * 128 + p * 16) = make_int4(0, 0, 0, 0);
            }
        }
    }
    const int keyadj = (j & 1) * 4;
    const char* src = (const char*)imsw + ((size_t)j * 36 + (l >> 3)) * 2048 + (l & 7) * 16;
    f32x4 acc[3][3];
#pragma unroll
    for (int m = 0; m < 3; ++m)
#pragma unroll
        for (int n = 0; n < 3; ++n) acc[m][n] = (f32x4){0.f, 0.f, 0.f, 0.f};

    for (int k0b = 0; k0b < 2048; k0b += 128) {
        asm volatile("s_waitcnt vmcnt(0) lgkmcnt(0)" ::: "memory");
        __syncthreads();
#pragma unroll
        for (int t = 0; t < 5; ++t) {
            if (t < 4 || l < 32) gload16(src + t * 8 * 2048 + k0b, sm + t * 1024);
        }
        asm volatile("s_waitcnt vmcnt(0)" ::: "memory");
        __syncthreads();
#pragma unroll
        for (int ks = 0; ks < 2; ++ks) {
            int swz = (((ks * 4 + grp) ^ ((lw + keyadj) & 7)) << 4);
            s16x8 fr[3];
#pragma unroll
            for (int m = 0; m < 3; ++m)
                fr[m] = *(const s16x8*)(sm + m * 2048 + lw * 128 + swz);
#pragma unroll
            for (int m = 0; m < 3; ++m)
#pragma unroll
                for (int n = 0; n < 3; ++n)
                    acc[m][n] = __builtin_amdgcn_mfma_f32_16x16x32_bf16(fr[m], fr[n], acc[m][n], 0, 0, 0);
        }
    }
#pragma unroll
    for (int m = 0; m < 3; ++m)
#pragma unroll
        for (int n = 0; n < 3; ++n)
#pragma unroll
            for (int reg = 0; reg < 4; ++reg)
                Gtmp[(m * 16 + grp * 4 + reg) * 52 + n * 16 + lw] = acc[m][n][reg];
    asm volatile("s_waitcnt lgkmcnt(0)" ::: "memory");
    __syncthreads();
    for (int t = 0; t < 6; ++t) {
        int idx = l + 64 * t;
        int row = idx >> 3, p = idx & 7;
        int k0 = (p ^ (row & 7)) * 8;
        ushort4 o0, o1;
        float v[8];
#pragma unroll
        for (int e = 0; e < 8; ++e) {
            int k = k0 + e;
            v[e] = (k < 48) ? Gtmp[row * 52 + k] : 0.f;
        }
        o0.x = f2bf(v[0]); o0.y = f2bf(v[1]); o0.z = f2bf(v[2]); o0.w = f2bf(v[3]);
        o1.x = f2bf(v[4]); o1.y = f2bf(v[5]); o1.z = f2bf(v[6]); o1.w = f2bf(v[7]);
        ushort4* dp = (ushort4*)((char*)Gsw + (size_t)j * 6144 + row * 128 + p * 16);
        dp[0] = o0; dp[1] = o1;
    }
}

// ---- main pair kernel: block = 8 images x 4 captions, 8 waves (2M x 4N) ----
// Wave tile 144x32 -> acc[9][2] = 72 VGPRs. R3-R7 used acc[9][4]=144 which the
// backend refused to keep resident (VGPR pinned at 128, ~105MB scratch traffic
// regardless of launch_bounds / waves_per_eu). Fit under the 128 ceiling instead.
__global__ __attribute__((amdgpu_flat_work_group_size(512, 512)))
__attribute__((amdgpu_waves_per_eu(2, 2)))
void pair4_kernel(const unsigned short* __restrict__ imsw,
                  const unsigned short* __restrict__ ssw,
                  const unsigned short* __restrict__ Gswp,
                  const float* __restrict__ w1g,
                  float* __restrict__ scores) {
    extern __shared__ char smem[];
    const int ig = blockIdx.x;   // caption quad
    const int jg = blockIdx.y;   // image octet
    const int tid = threadIdx.x;
    const int l = tid & 63, wv = tid >> 6;
    const int grp = l >> 4, lw = l & 15;
    const int wm = wv >> 2, wn = wv & 3;

    const char* aSrc = (const char*)imsw + ((size_t)(jg * 288) + (l >> 3)) * 2048 + (l & 7) * 16;
    const char* bSrc = (const char*)ssw + ((size_t)(ig * 128) + (l >> 3)) * 2048 + (l & 7) * 16;

    f32x4 acc[9][2];
#pragma unroll
    for (int m = 0; m < 9; ++m)
#pragma unroll
        for (int n = 0; n < 2; ++n) acc[m][n] = (f32x4){0.f, 0.f, 0.f, 0.f};

    auto stage = [&](int bb, int k0b) {
        char* ab = smem + bb;
#pragma unroll
        for (int t = 0; t < 5; ++t) {
            int ii = wv + 8 * t;
            if (ii < 36) gload16(aSrc + (size_t)ii * 16384 + k0b, ab + ii * 1024);
        }
        char* bbp = smem + bb + BOFF;
#pragma unroll
        for (int t = 0; t < 2; ++t) {
            int ii = wv + 8 * t;
            gload16(bSrc + (size_t)ii * 16384 + k0b, bbp + ii * 1024);
        }
    };
    auto compute = [&](int bb) {
        const char* A = smem + bb;
        const char* B = smem + bb + BOFF;
#pragma unroll
        for (int ks = 0; ks < 2; ++ks) {
            const int swz = (((ks * 4 + grp) ^ (lw & 7)) << 4);
            s16x8 b0 = *(const s16x8*)(B + (wn * 32 + lw) * 128 + swz);
            s16x8 b1 = *(const s16x8*)(B + (wn * 32 + 16 + lw) * 128 + swz);
#pragma unroll
            for (int m = 0; m < 9; ++m) {
                s16x8 a = *(const s16x8*)(A + (wm * 144 + m * 16 + lw) * 128 + swz);
                acc[m][0] = __builtin_amdgcn_mfma_f32_16x16x32_bf16(a, b0, acc[m][0], 0, 0, 0);
                acc[m][1] = __builtin_amdgcn_mfma_f32_16x16x32_bf16(a, b1, acc[m][1], 0, 0, 0);
            }
        }
    };

    stage(0, 0);
    asm volatile("s_waitcnt vmcnt(0)" ::: "memory");
    __syncthreads();
    for (int t = 0; t < 16; ++t) {
        if (t < 15) {
            stage(((t + 1) & 1) * BUFSZ, (t + 1) * 128);
        } else {
            // prefetch Gram tiles for the 8 images into dead buf0
            const char* gB = (const char*)Gswp + (size_t)jg * 49152 + l * 16;
#pragma unroll
            for (int u = 0; u < 6; ++u) {
                int ii = wv + 8 * u;
                gload16(gB + (size_t)ii * 1024, smem + ii * 1024);
            }
        }
        compute((t & 1) * BUFSZ);
        asm volatile("s_waitcnt vmcnt(0)" ::: "memory");
        __syncthreads();
    }

    // ================= barrier-free per-wave epilogue =================
    // wave (wm,wn): rows wm*144..+144 (images wm*4..+4), caption ig*4+wn
    char* const myE = smem + E_OFF + wv * 4096;
    float* NB = (float*)(smem + NB_OFF);

    // zero E pads (regions 36..63) for my slot
#pragma unroll
    for (int u = 0; u < 7; ++u) {
        int e = l + u * 64;               // 448 = 32w * 14 pairs
        int w = e / 14, pr = e - w * 14 + 18;
        *(unsigned*)(myE + w * 128 + (((pr >> 2) ^ (w & 7)) << 4) + (pr & 3) * 4) = 0u;
    }

    // P1: inverse region norms (leaky, over 32 words) -> NB[cap][288] (wave-local)
#pragma unroll
    for (int m = 0; m < 9; ++m)
#pragma unroll
        for (int reg = 0; reg < 4; ++reg) {
            int rowL = m * 16 + grp * 4 + reg;
            float a0 = acc[m][0][reg], a1 = acc[m][1][reg];
            float l0 = a0 > 0.f ? a0 : 0.1f * a0;
            float l1 = a1 > 0.f ? a1 : 0.1f * a1;
            float ss = l0 * l0 + l1 * l1;
            ss += __shfl_xor(ss, 1); ss += __shfl_xor(ss, 2);
            ss += __shfl_xor(ss, 4); ss += __shfl_xor(ss, 8);
            if (lw == 0)
                NB[wn * 288 + wm * 144 + rowL] = 1.f / (sqrtf(ss) + EPSF);
        }

    // P2: per-local-image per-word max logit
    float mx[4][2];
#pragma unroll
    for (int a = 0; a < 4; ++a)
#pragma unroll
        for (int b = 0; b < 2; ++b) mx[a][b] = -1e30f;
#pragma unroll
    for (int m = 0; m < 9; ++m) {
        int rbase = m * 16 + grp * 4;
        int img = (rbase * 1821) >> 16;      // rbase / 36
        float4 iv = *(const float4*)&NB[wn * 288 + wm * 144 + rbase];
        float ivr[4] = {iv.x, iv.y, iv.z, iv.w};
#pragma unroll
        for (int n = 0; n < 2; ++n) {
            float t4 = -1e30f;
#pragma unroll
            for (int reg = 0; reg < 4; ++reg) {
                float a = acc[m][n][reg];
                float lk = a > 0.f ? a : 0.1f * a;
                t4 = fmaxf(t4, LAM_SM * lk * ivr[reg]);
            }
#pragma unroll
            for (int mm = 0; mm < 4; ++mm)
                mx[mm][n] = (img == mm) ? fmaxf(mx[mm][n], t4) : mx[mm][n];
        }
    }
#pragma unroll
    for (int a = 0; a < 4; ++a)
#pragma unroll
        for (int b = 0; b < 2; ++b) {
            mx[a][b] = fmaxf(mx[a][b], __shfl_xor(mx[a][b], 16));
            mx[a][b] = fmaxf(mx[a][b], __shfl_xor(mx[a][b], 32));
        }

    float w1v[2];
#pragma unroll
    for (int n = 0; n < 2; ++n)
        w1v[n] = w1g[(ig * 4 + wn) * 32 + n * 16 + lw];

#pragma unroll
    for (int L = 0; L < 4; ++L) {
        float dn[2] = {0.f, 0.f}, nm[2] = {0.f, 0.f};
        // P3: e = exp(t - mx), accumulate den/num, write E (bf16)
        // image L's rows live in m = 2L, 2L+1, 2L+2 — static indices (rule #20)
#pragma unroll
        for (int mm3 = 0; mm3 < 3; ++mm3) {
            const int m = 2 * L + mm3;
            int rbase = m * 16 + grp * 4;
            int img = (rbase * 1821) >> 16;
            bool pred = (img == L);
            int rp0 = rbase - L * 36;
            float4 iv = *(const float4*)&NB[wn * 288 + wm * 144 + rbase];
            float ivr[4] = {iv.x, iv.y, iv.z, iv.w};
#pragma unroll
            for (int n = 0; n < 2; ++n) {
                int w = n * 16 + lw;
                float e[4];
#pragma unroll
                for (int reg = 0; reg < 4; ++reg) {
                    float a = acc[m][n][reg];
                    float lk = a > 0.f ? a : 0.1f * a;
                    float tl = LAM_SM * lk * ivr[reg];
                    e[reg] = pred ? __expf(tl - mx[L][n]) : 0.f;
                    dn[n] += e[reg];
                    nm[n] += e[reg] * a;
                }
                if (pred) {
                    char* base = myE + w * 128 + (((rp0 >> 3) ^ (w & 7)) << 4) + (rp0 & 7) * 2;
                    *(unsigned*)(base) = pack2bf(e[0], e[1]);
                    *(unsigned*)(base + 4) = pack2bf(e[2], e[3]);
                }
            }
        }
#pragma unroll
        for (int n = 0; n < 2; ++n) {
            dn[n] += __shfl_xor(dn[n], 16); dn[n] += __shfl_xor(dn[n], 32);
            nm[n] += __shfl_xor(nm[n], 16); nm[n] += __shfl_xor(nm[n], 32);
        }
        // P4: U = Gd[img] x E ; q = sum E .* U
        const char* Gd = smem + (wm * 4 + L) * 6144;
        f32x4 u[3][2];
#pragma unroll
        for (int m = 0; m < 3; ++m)
#pragma unroll
            for (int n = 0; n < 2; ++n) u[m][n] = (f32x4){0.f, 0.f, 0.f, 0.f};
#pragma unroll
        for (int ks = 0; ks < 2; ++ks) {
            int swz = (((ks * 4 + grp) ^ (lw & 7)) << 4);
            s16x8 ga[3], eb[2];
#pragma unroll
            for (int m = 0; m < 3; ++m)
                ga[m] = *(const s16x8*)(Gd + (m * 16 + lw) * 128 + swz);
#pragma unroll
            for (int n = 0; n < 2; ++n) {
                int w = n * 16 + lw;
                eb[n] = *(const s16x8*)(myE + w * 128 + (((ks * 4 + grp) ^ (w & 7)) << 4));
            }
#pragma unroll
            for (int m = 0; m < 3; ++m)
#pragma unroll
                for (int n = 0; n < 2; ++n)
                    u[m][n] = __builtin_amdgcn_mfma_f32_16x16x32_bf16(ga[m], eb[n], u[m][n], 0, 0, 0);
        }
        float qq[2] = {0.f, 0.f};
#pragma unroll
        for (int m = 0; m < 3; ++m)
#pragma unroll
            for (int n = 0; n < 2; ++n) {
                int w = n * 16 + lw;
                const char* base = myE + w * 128;
#pragma unroll
                for (int rg = 0; rg < 4; rg += 2) {
                    int rp = m * 16 + grp * 4 + rg;
                    unsigned pv = *(const unsigned*)(base + (((rp >> 3) ^ (w & 7)) << 4) + (rp & 7) * 2);
                    qq[n] += u[m][n][rg] * bf2f(pv) + u[m][n][rg + 1] * bf2f(pv >> 16);
                }
            }
#pragma unroll
        for (int n = 0; n < 2; ++n) {
            qq[n] += __shfl_xor(qq[n], 16); qq[n] += __shfl_xor(qq[n], 32);
        }
        // P5: cosine sim + LSE over 32 words -> score
        float s0 = nm[0] / fmaxf(w1v[0] * sqrtf(fmaxf(qq[0], 0.f)), EPSF * dn[0]);
        float s1 = nm[1] / fmaxf(w1v[1] * sqrtf(fmaxf(qq[1], 0.f)), EPSF * dn[1]);
        float m2 = fmaxf(s0, s1);
        m2 = fmaxf(m2, __shfl_xor(m2, 1)); m2 = fmaxf(m2, __shfl_xor(m2, 2));
        m2 = fmaxf(m2, __shfl_xor(m2, 4)); m2 = fmaxf(m2, __shfl_xor(m2, 8));
        float ssum = __expf(LAM_LSE * (s0 - m2)) + __expf(LAM_LSE * (s1 - m2));
        ssum += __shfl_xor(ssum, 1); ssum += __shfl_xor(ssum, 2);
        ssum += __shfl_xor(ssum, 4); ssum += __shfl_xor(ssum, 8);
        if (l == 0)
            scores[(size_t)(jg * 8 + wm * 4 + L) * NI + ig * 4 + wn] =
                m2 + logf(ssum) / LAM_LSE;
    }
}

// ---- final hinge loss over the 128x128 score matrix ----
__global__ __launch_bounds__(256) void loss_kernel(const float* __restrict__ scores,
                                                   float* __restrict__ out) {
    __shared__ float diag[NJ];
    __shared__ float part[256];
    const int tid = threadIdx.x;
    if (tid < NJ) diag[tid] = scores[tid * NI + tid];
    __syncthreads();
    float m = 0.f;
    if (tid < 128) {
        const int a = tid;
        const float da = diag[a];
        for (int b = 0; b < NI; ++b) {
            if (b == a) continue;
            float c = MARGIN + scores[a * NI + b] - da;
            m = fmaxf(m, c);
        }
    } else {
        const int b = tid - 128;
        const float db = diag[b];
        for (int a = 0; a < NJ; ++a) {
            if (a == b) continue;
            float c = MARGIN + scores[a * NI + b] - db;
            m = fmaxf(m, c);
        }
    }
    part[tid] = m;
    __syncthreads();
    for (int st = 128; st > 0; st >>= 1) {
        if (tid < st) part[tid] += part[tid + st];
        __syncthreads();
    }
    if (tid == 0) out[0] = part[0];
}

extern "C" void kernel_launch(void* const* d_in, const int* in_sizes, int n_in,
                              void* d_out, int out_size, void* d_ws, size_t ws_size,
                              hipStream_t stream) {
    const float* im = (const float*)d_in[0];
    const float* s = (const float*)d_in[1];

    unsigned short* imsw = (unsigned short*)d_ws;
    unsigned short* ssw = imsw + IM_ELEMS;
    unsigned short* Gswp = ssw + S_ELEMS;
    float* w1 = (float*)(Gswp + GSW_ELEMS);
    float* scores = w1 + S_ROWS;

    hipFuncSetAttribute((const void*)pair4_kernel,
                        hipFuncAttributeMaxDynamicSharedMemorySize, SMEM_TOTAL);

    cvtswz_kernel<<<dim3(IM_ROWS * 128 / 256), dim3(256), 0, stream>>>(im, imsw);
    cvtswz_kernel<<<dim3(S_ROWS * 128 / 256), dim3(256), 0, stream>>>(s, ssw);
    wnorm_kernel<<<dim3(NI), dim3(256), 0, stream>>>(s, w1);
    gram_mfma_kernel<<<dim3(NJ), dim3(64), 0, stream>>>(imsw, Gswp);
    pair4_kernel<<<dim3(NI / 4, NJ / 8), dim3(512), SMEM_TOTAL, stream>>>(imsw, ssw, Gswp, w1, scores);
    loss_kernel<<<dim3(1), dim3(256), 0, stream>>>(scores, (float*)d_out);
}